// Round 1
// baseline (509.653 us; speedup 1.0000x reference)
//
#include <hip/hip_runtime.h>

#define EMBED 100
#define MATSZ (EMBED * EMBED)   // 10000 floats per functor matrix
#define NVEC4 (MATSZ / 4)       // 2500 float4 per matrix (rows are 25 float4, 16B-aligned)
#define BLOCK 256

__global__ __launch_bounds__(BLOCK) void msg_kernel(
    const int* __restrict__ Xa,
    const int* __restrict__ Xf,
    const int* __restrict__ Xc,
    const float* __restrict__ noun_matrix,    // [50000, 100]
    const float* __restrict__ functor_table,  // [10000, 10000]
    const float* __restrict__ context_table,  // [50000, 100]
    float* __restrict__ out)                  // [B]
{
    const int b   = blockIdx.x;
    const int tid = threadIdx.x;

    __shared__ float s_arg[EMBED];
    __shared__ float s_ctx[EMBED];
    __shared__ float s_part[BLOCK / 64];

    const int ia = Xa[b];
    const int ifn = Xf[b];
    const int ic = Xc[b];

    // Stage the two 100-float vectors in LDS (coalesced-enough, tiny).
    if (tid < EMBED) {
        s_arg[tid] = noun_matrix[(size_t)ia * EMBED + tid];
        s_ctx[tid] = context_table[(size_t)ic * EMBED + tid];
    }
    __syncthreads();

    // Stride over the 100x100 matrix as float4s. Since 100 % 4 == 0 and the
    // matrix base offset (ifn * 40000 B) is 16B-aligned, each float4 sits
    // entirely inside one row i = f/100.
    const float4* __restrict__ M4 =
        (const float4*)(functor_table + (size_t)ifn * MATSZ);

    float acc = 0.0f;
    for (int v = tid; v < NVEC4; v += BLOCK) {
        float4 m = M4[v];
        int f = v * 4;
        int i = f / EMBED;          // row (ctx index) — compiler magic-muls
        int j = f - i * EMBED;      // col (arg index), 0..96 step 4
        float dot4 = m.x * s_arg[j]     + m.y * s_arg[j + 1]
                   + m.z * s_arg[j + 2] + m.w * s_arg[j + 3];
        acc = fmaf(s_ctx[i], dot4, acc);
    }

    // Wave64 shuffle reduction, then cross-wave via LDS.
    #pragma unroll
    for (int off = 32; off > 0; off >>= 1)
        acc += __shfl_down(acc, off, 64);

    const int wave = tid >> 6;
    const int lane = tid & 63;
    if (lane == 0) s_part[wave] = acc;
    __syncthreads();

    if (tid == 0) {
        float r = 0.0f;
        #pragma unroll
        for (int w = 0; w < BLOCK / 64; ++w) r += s_part[w];
        out[b] = r;
    }
}

extern "C" void kernel_launch(void* const* d_in, const int* in_sizes, int n_in,
                              void* d_out, int out_size, void* d_ws, size_t ws_size,
                              hipStream_t stream) {
    const int*   Xa   = (const int*)d_in[0];
    const int*   Xf   = (const int*)d_in[1];
    const int*   Xc   = (const int*)d_in[2];
    const float* noun = (const float*)d_in[3];
    const float* func = (const float*)d_in[4];
    const float* ctxt = (const float*)d_in[5];
    float*       out  = (float*)d_out;

    const int B = in_sizes[0];   // 8192
    msg_kernel<<<B, BLOCK, 0, stream>>>(Xa, Xf, Xc, noun, func, ctxt, out);
}

// Round 2
// 509.408 us; speedup vs baseline: 1.0005x; 1.0005x over previous
//
#include <hip/hip_runtime.h>

#define EMBED 100
#define MATSZ (EMBED * EMBED)   // 10000 floats per functor matrix
#define NVEC4 (MATSZ / 4)       // 2500 float4 per matrix
#define BLOCK 256
#define ITERS 10                // ceil(NVEC4 / BLOCK) — compile-time constant

__global__ __launch_bounds__(BLOCK) void msg_kernel(
    const int* __restrict__ Xa,
    const int* __restrict__ Xf,
    const int* __restrict__ Xc,
    const float* __restrict__ noun_matrix,    // [50000, 100]
    const float* __restrict__ functor_table,  // [10000, 10000]
    const float* __restrict__ context_table,  // [50000, 100]
    float* __restrict__ out)                  // [B]
{
    const int b   = blockIdx.x;
    const int tid = threadIdx.x;

    __shared__ float4 s_arg4[EMBED / 4];   // arg vector as 25 float4
    __shared__ float  s_ctx[EMBED];
    __shared__ float  s_part[BLOCK / 64];

    const int ia  = Xa[b];
    const int ifn = Xf[b];
    const int ic  = Xc[b];

    // Stage vectors. Rows are 400 B (16B-aligned), so float4 loads are legal.
    if (tid < EMBED / 4) {
        s_arg4[tid] = ((const float4*)(noun_matrix + (size_t)ia * EMBED))[tid];
    }
    if (tid < EMBED) {
        s_ctx[tid] = context_table[(size_t)ic * EMBED + tid];
    }
    __syncthreads();

    const float4* __restrict__ M4 =
        (const float4*)(functor_table + (size_t)ifn * MATSZ);

    // Issue ALL matrix loads up front (constant trip count, clamped index,
    // masked contribution) so 10 global_load_dwordx4 are in flight per thread
    // before any waitcnt — memory-level parallelism instead of serial
    // load→use→load→use.
    float4 mv[ITERS];
    #pragma unroll
    for (int k = 0; k < ITERS; ++k) {
        int v  = tid + k * BLOCK;
        int vc = v < NVEC4 ? v : (NVEC4 - 1);   // clamped: always in-bounds
        mv[k] = M4[vc];
    }

    float acc = 0.0f;
    #pragma unroll
    for (int k = 0; k < ITERS; ++k) {
        int v  = tid + k * BLOCK;
        int vc = v < NVEC4 ? v : (NVEC4 - 1);
        int f  = vc * 4;
        int i  = f / EMBED;          // row (ctx index)
        int j  = f - i * EMBED;      // col (arg index), multiple of 4
        float4 a = s_arg4[j >> 2];   // single ds_read_b128
        float4 m = mv[k];
        float dot4 = m.x * a.x + m.y * a.y + m.z * a.z + m.w * a.w;
        float c = (v < NVEC4) ? s_ctx[i] : 0.0f;
        acc = fmaf(c, dot4, acc);
    }

    // Wave64 shuffle reduction, then cross-wave via LDS.
    #pragma unroll
    for (int off = 32; off > 0; off >>= 1)
        acc += __shfl_down(acc, off, 64);

    const int wave = tid >> 6;
    const int lane = tid & 63;
    if (lane == 0) s_part[wave] = acc;
    __syncthreads();

    if (tid == 0) {
        float r = 0.0f;
        #pragma unroll
        for (int w = 0; w < BLOCK / 64; ++w) r += s_part[w];
        out[b] = r;
    }
}

extern "C" void kernel_launch(void* const* d_in, const int* in_sizes, int n_in,
                              void* d_out, int out_size, void* d_ws, size_t ws_size,
                              hipStream_t stream) {
    const int*   Xa   = (const int*)d_in[0];
    const int*   Xf   = (const int*)d_in[1];
    const int*   Xc   = (const int*)d_in[2];
    const float* noun = (const float*)d_in[3];
    const float* func = (const float*)d_in[4];
    const float* ctxt = (const float*)d_in[5];
    float*       out  = (float*)d_out;

    const int B = in_sizes[0];   // 8192
    msg_kernel<<<B, BLOCK, 0, stream>>>(Xa, Xf, Xc, noun, func, ctxt, out);
}